// Round 12
// baseline (225.747 us; speedup 1.0000x reference)
//
#include <hip/hip_runtime.h>
#include <hip/hip_bf16.h>
#include <math.h>

#define D_MODEL 1024
#define HS 2048
#define HE 1024
#define NEXP 8
#define NTOK 4096
#define NSLOT 8192

typedef __attribute__((ext_vector_type(4))) float f32x4;
typedef __attribute__((ext_vector_type(8))) short bf16x8;

__device__ __forceinline__ short f2b(float f) {
  __hip_bfloat16 h = __float2bfloat16(f);
  return *reinterpret_cast<short*>(&h);
}
__device__ __forceinline__ float b2f(short s) {
  return __bfloat162float(*reinterpret_cast<__hip_bfloat16*>(&s));
}

__device__ __forceinline__ void gl_lds16(const short* g, short* l) {
  __builtin_amdgcn_global_load_lds(
      (const __attribute__((address_space(1))) void*)g,
      (__attribute__((address_space(3))) void*)l, 16, 0, 0);
}

// shared transpose tile body: in [R][C] f32 -> out bf16 transposed.
__device__ __forceinline__ void tr_tile(const float* __restrict__ in,
                                        short* __restrict__ out, int R, int C,
                                        int bx, int by, int bz, int rmap,
                                        float (*tile)[69], int t) {
  const int c0 = bx * 64;
  const int r0 = by * 64;
  const size_t bo = (size_t)bz * R * C;
  const int lr = t >> 4;
  const int lc4 = (t & 15) * 4;
#pragma unroll
  for (int i = 0; i < 4; i++) {
    const float4 v = *(const float4*)&in[bo + (size_t)(r0 + lr + i * 16) * C + c0 + lc4];
    tile[lc4 + 0][lr + i * 16] = v.x;
    tile[lc4 + 1][lr + i * 16] = v.y;
    tile[lc4 + 2][lr + i * 16] = v.z;
    tile[lc4 + 3][lr + i * 16] = v.w;
  }
  __syncthreads();
#pragma unroll
  for (int i = 0; i < 4; i++) {
    const int oc = (t >> 4) + i * 16;
    const int or4 = (t & 15) * 4;
    short4 o;
    o.x = f2b(tile[oc][or4 + 0]);
    o.y = f2b(tile[oc][or4 + 1]);
    o.z = f2b(tile[oc][or4 + 2]);
    o.w = f2b(tile[oc][or4 + 3]);
    const int c = c0 + oc;
    size_t orow;
    if (rmap == 0) orow = bo + (size_t)c * R;
    else orow = (size_t)((c >> 5) * 64 + (rmap == 2 ? 32 : 0) + (c & 31)) * R;
    *(short4*)&out[orow + r0 + or4] = o;
  }
}

__global__ __launch_bounds__(256) void tr_w13(const float* __restrict__ w1,
                                              const float* __restrict__ w3,
                                              short* __restrict__ w13I) {
  __shared__ float tile[64][69];
  const int z = blockIdx.z;
  tr_tile(z ? w3 : w1, w13I, D_MODEL, HS, blockIdx.x, blockIdx.y, 0, z ? 2 : 1,
          tile, threadIdx.x);
}

__global__ __launch_bounds__(256) void tr_w2(const float* __restrict__ w2,
                                             short* __restrict__ w2T) {
  __shared__ float tile[64][69];
  tr_tile(w2, w2T, HS, D_MODEL, blockIdx.x, blockIdx.y, 0, 0, tile, threadIdx.x);
}

__global__ __launch_bounds__(256) void tr_exp(const float* __restrict__ W1e,
                                              const float* __restrict__ W2e,
                                              short* __restrict__ W1eT,
                                              short* __restrict__ W2eT) {
  __shared__ float tile[64][69];
  const int z = blockIdx.z;
  if (z < 8)
    tr_tile(W1e, W1eT, D_MODEL, HE, blockIdx.x, blockIdx.y, z, 0, tile, threadIdx.x);
  else
    tr_tile(W2e, W2eT, HE, D_MODEL, blockIdx.x, blockIdx.y, z - 8, 0, tile, threadIdx.x);
}

// ------- router + x->bf16 convert fused -------
__global__ __launch_bounds__(256) void router_kernel(
    const float* __restrict__ x, const float* __restrict__ temb,
    const float* __restrict__ rw, const float* __restrict__ rbias,
    short* __restrict__ xb, int* __restrict__ topk, float* __restrict__ gates) {
  const int t = (blockIdx.x * 256 + threadIdx.x) >> 6;
  const int lane = threadIdx.x & 63;
  const float* xr = x + (size_t)t * D_MODEL;
  const float* tr = temb + (size_t)(t >> 10) * D_MODEL;  // T=1024
  float acc[NEXP] = {};
#pragma unroll
  for (int i = 0; i < 4; i++) {
    const int j = i * 256 + lane * 4;
    const float4 xv = *(const float4*)&xr[j];
    const float4 tv = *(const float4*)&tr[j];
    short4 o;
    o.x = f2b(xv.x); o.y = f2b(xv.y); o.z = f2b(xv.z); o.w = f2b(xv.w);
    *(short4*)&xb[(size_t)t * D_MODEL + j] = o;
    const float* wx = rw + (size_t)j * NEXP;
    const float* wt = rw + (size_t)(D_MODEL + j) * NEXP;
    const float xa[4] = {xv.x, xv.y, xv.z, xv.w};
    const float ta[4] = {tv.x, tv.y, tv.z, tv.w};
#pragma unroll
    for (int u = 0; u < 4; u++)
#pragma unroll
      for (int e = 0; e < NEXP; e++)
        acc[e] += xa[u] * wx[u * NEXP + e] + ta[u] * wt[u * NEXP + e];
  }
#pragma unroll
  for (int off = 32; off; off >>= 1)
#pragma unroll
    for (int e = 0; e < NEXP; e++) acc[e] += __shfl_xor(acc[e], off);
  if (lane == 0) {
    float s[NEXP], sel[NEXP];
#pragma unroll
    for (int e = 0; e < NEXP; e++) {
      s[e] = 1.f / (1.f + expf(-acc[e]));
      sel[e] = s[e] + rbias[e];
    }
    int i0 = 0;
#pragma unroll
    for (int e = 1; e < NEXP; e++) if (sel[e] > sel[i0]) i0 = e;
    int i1 = (i0 == 0) ? 1 : 0;
#pragma unroll
    for (int e = 0; e < NEXP; e++) if (e != i0 && sel[e] > sel[i1]) i1 = e;
    float s0 = s[i0], s1 = s[i1], den = s0 + s1;
    float g0, g1;
    if (den > 1e-9f) { g0 = s0 / (den + 1e-9f); g1 = s1 / (den + 1e-9f); }
    else { g0 = 0.5f; g1 = 0.5f; }
    topk[t * 2] = i0; topk[t * 2 + 1] = i1;
    gates[t * 2] = g0; gates[t * 2 + 1] = g1;
  }
}

// ------- grouping: hist + scan + fill + BM=128 tile table (ntile <= 72) ------
__global__ __launch_bounds__(1024) void group_kernel(const int* __restrict__ topk,
                                                     int* __restrict__ perm,
                                                     int* __restrict__ offs,
                                                     int* __restrict__ te,
                                                     int* __restrict__ tm,
                                                     int* __restrict__ ntile) {
  __shared__ int cnt[NEXP], cur[NEXP];
  const int t = threadIdx.x;
  if (t < NEXP) cnt[t] = 0;
  __syncthreads();
  int mye[8];
#pragma unroll
  for (int i = 0; i < 8; i++) {
    mye[i] = topk[i * 1024 + t];
    atomicAdd(&cnt[mye[i]], 1);
  }
  __syncthreads();
  if (t == 0) {
    int a = 0;
    for (int e = 0; e < NEXP; e++) { offs[e] = a; cur[e] = a; a += cnt[e]; }
    offs[NEXP] = a;
    int nt = 0;
    for (int e = 0; e < NEXP; e++)
      for (int m0 = 0; m0 < cnt[e]; m0 += 128) { te[nt] = e; tm[nt] = m0; nt++; }
    ntile[0] = nt;  // <= 72
  }
  __syncthreads();
#pragma unroll
  for (int i = 0; i < 8; i++) {
    int pos = atomicAdd(&cur[mye[i]], 1);
    perm[pos] = i * 1024 + t;
  }
}

// ====== unified 128x128 BK=64 counted-2-barrier GEMM, 2 blocks/CU ======
// (g2_ct template generalized — R11 evidence: this config = 3.8 TF/CU vs
//  256²/1-block/CU = 2.9 TF/CU; independent blocks de-lockstep the barriers.)
// MODE 0 (G1): A=xb, B=w13I, silu-pair -> ubuf. grid 1024.
// MODE 1: A=xb gathered perm>>1, B=W1eT[e], GELU -> hexpb[gi]. grid 576.
// MODE 2: A=hexpb slot-dense, B=W2eT[e], gate-scatter -> yb. grid 576.
// MODE 3 (G2): A=ubuf, B=w2T, combine(+yb) -> out f32. grid 256.
// LDS 64 KiB: 2 buf x {A[128][64] | B[128][64]} swizzled. 4 waves (2m x 2n).
template <int MODE, int NT>
__global__ __launch_bounds__(256, 2) void g128(
    const short* __restrict__ A, const short* __restrict__ B, void* __restrict__ Cout,
    const int* __restrict__ perm, const int* __restrict__ offs,
    const float* __restrict__ gates, const int* __restrict__ te,
    const int* __restrict__ tm, const int* __restrict__ ntile,
    const short* __restrict__ yb) {
  extern __shared__ short lds[];
  const int td = threadIdx.x;
  const int K = NT * 64;

  int m_panel = 0, n_panel = 0, e = 0, m0 = 0, rbeg = 0, rend = 0, bxn = 0;
  const short* Bbase;
  if (MODE == 0) {
    const int xcd = blockIdx.x & 7, w = blockIdx.x >> 3;  // grid 1024
    n_panel = xcd * 4 + (w >> 5);  // 0..31 (B panels XCD-local)
    m_panel = w & 31;              // 0..31
    Bbase = B + (size_t)n_panel * 128 * K;
  } else if (MODE == 3) {
    const int xcd = blockIdx.x & 7, slot = blockIdx.x >> 3;  // grid 256
    n_panel = slot & 7;                // 8 panels (D_MODEL/128)
    m_panel = xcd * 4 + (slot >> 3);   // 32 panels
    Bbase = B + (size_t)n_panel * 128 * K;
  } else {
    const int ty = blockIdx.x >> 3;    // grid 576
    if (ty >= ntile[0]) return;
    bxn = blockIdx.x & 7;
    e = te[ty];
    m0 = tm[ty];
    rbeg = offs[e]; rend = offs[e + 1];
    Bbase = B + ((size_t)e * 1024 + bxn * 128) * K;
  }

  const int srow = td >> 3;                      // 0..31
  const int colsw8 = ((td & 7) ^ (srow & 7)) * 8;
  const short* ap[4];
  const short* bp[4];
#pragma unroll
  for (int u = 0; u < 4; u++) {
    const int trow = u * 32 + srow;
    int grow;
    if (MODE == 0) grow = m_panel * 128 + trow;
    else if (MODE == 1) grow = perm[min(rbeg + m0 + trow, rend - 1)] >> 1;
    else if (MODE == 2) grow = min(rbeg + m0 + trow, rend - 1);
    else grow = m_panel * 128 + trow;
    ap[u] = A + (size_t)grow * K + colsw8;
    bp[u] = Bbase + (size_t)trow * K + colsw8;
  }

#define STAGE(t_, b_)                                                      \
  do {                                                                     \
    gl_lds16(ap[0] + (t_) * 64, lds + (b_) * 16384 + td * 8);              \
    gl_lds16(ap[1] + (t_) * 64, lds + (b_) * 16384 + 2048 + td * 8);       \
    gl_lds16(ap[2] + (t_) * 64, lds + (b_) * 16384 + 4096 + td * 8);       \
    gl_lds16(ap[3] + (t_) * 64, lds + (b_) * 16384 + 6144 + td * 8);       \
    gl_lds16(bp[0] + (t_) * 64, lds + (b_) * 16384 + 8192 + td * 8);       \
    gl_lds16(bp[1] + (t_) * 64, lds + (b_) * 16384 + 10240 + td * 8);      \
    gl_lds16(bp[2] + (t_) * 64, lds + (b_) * 16384 + 12288 + td * 8);      \
    gl_lds16(bp[3] + (t_) * 64, lds + (b_) * 16384 + 14336 + td * 8);      \
  } while (0)

  const int l = td & 63;
  const int wv = td >> 6;
  const int wm = (wv >> 1) * 64, wn = (wv & 1) * 64;
  const int lr = l & 15;
  const int swzk0 = ((0 + (l >> 4) * 16) ^ ((l & 7) << 4)) >> 1;
  const int swzk1 = ((64 + (l >> 4) * 16) ^ ((l & 7) << 4)) >> 1;

#define LDA(mf_, swz_) (*(const bf16x8*)&Ah[(unsigned)(((mf_)*16 + lr) * 64) + (swz_)])
#define LDB(nf_, swz_) (*(const bf16x8*)&Bh[(unsigned)(((nf_)*16 + lr) * 64) + (swz_)])
#define MMROW(mf_, a_)                                                                 \
  acc[mf_][0] = __builtin_amdgcn_mfma_f32_16x16x32_bf16(a_, b0, acc[mf_][0], 0, 0, 0); \
  acc[mf_][1] = __builtin_amdgcn_mfma_f32_16x16x32_bf16(a_, b1, acc[mf_][1], 0, 0, 0); \
  acc[mf_][2] = __builtin_amdgcn_mfma_f32_16x16x32_bf16(a_, b2, acc[mf_][2], 0, 0, 0); \
  acc[mf_][3] = __builtin_amdgcn_mfma_f32_16x16x32_bf16(a_, b3, acc[mf_][3], 0, 0, 0)

  f32x4 acc[4][4] = {};

  STAGE(0, 0);
  for (int t = 0; t < NT; ++t) {
    const int p = t & 1, q = p ^ 1;
    const short* Ah = lds + p * 16384 + wm * 64;
    const short* Bh = lds + p * 16384 + 8192 + wn * 64;
    if (t < NT - 1) {
      STAGE(t + 1, q);
      asm volatile("s_waitcnt vmcnt(8)" ::: "memory");
    } else {
      asm volatile("s_waitcnt vmcnt(0)" ::: "memory");
    }
    __builtin_amdgcn_s_barrier();
    {
      bf16x8 b0, b1, b2, b3, a0, a1, a2, a3;
      b0 = LDB(0, swzk0); b1 = LDB(1, swzk0); b2 = LDB(2, swzk0); b3 = LDB(3, swzk0);
      a0 = LDA(0, swzk0); a1 = LDA(1, swzk0); a2 = LDA(2, swzk0); a3 = LDA(3, swzk0);
      __builtin_amdgcn_s_setprio(1);
      MMROW(0, a0); MMROW(1, a1); MMROW(2, a2); MMROW(3, a3);
      __builtin_amdgcn_s_setprio(0);
      b0 = LDB(0, swzk1); b1 = LDB(1, swzk1); b2 = LDB(2, swzk1); b3 = LDB(3, swzk1);
      a0 = LDA(0, swzk1); a1 = LDA(1, swzk1); a2 = LDA(2, swzk1); a3 = LDA(3, swzk1);
      __builtin_amdgcn_s_setprio(1);
      MMROW(0, a0); MMROW(1, a1); MMROW(2, a2); MMROW(3, a3);
      __builtin_amdgcn_s_setprio(0);
    }
    __builtin_amdgcn_sched_barrier(0);
    __builtin_amdgcn_s_barrier();
  }

  // ---- epilogue ----
  const int rq = (l >> 4) * 4;
  if (MODE == 0) {
    // wave wn covers w13I rows [n_panel*128 + wn, +64): nf 0,1 = w1 cols,
    // nf 2,3 = w3 (same cols). u col = n_panel*64 + (wn>>1) + nf*16 + lr.
#pragma unroll
    for (int mf = 0; mf < 4; mf++)
#pragma unroll
      for (int j = 0; j < 4; j++) {
        const int row = m_panel * 128 + wm + mf * 16 + rq + j;
        short* Up = (short*)Cout + (size_t)row * HS + n_panel * 64 + (wn >> 1) + lr;
#pragma unroll
        for (int nf = 0; nf < 2; nf++) {
          const float a = acc[mf][nf][j];
          const float b = acc[mf][nf + 2][j];
          Up[nf * 16] = f2b(a / (1.f + expf(-a)) * b);
        }
      }
  } else if (MODE == 1) {
#pragma unroll
    for (int mf = 0; mf < 4; mf++)
#pragma unroll
      for (int j = 0; j < 4; j++) {
        const int gi = rbeg + m0 + wm + mf * 16 + rq + j;
        if (gi < rend) {
          short* Cp = (short*)Cout + (size_t)gi * HE + bxn * 128 + wn + lr;
#pragma unroll
          for (int nf = 0; nf < 4; nf++) {
            const float v = acc[mf][nf][j];
            Cp[nf * 16] = f2b(0.5f * v * (1.0f + erff(v * 0.70710678118654752f)));
          }
        }
      }
  } else if (MODE == 2) {
#pragma unroll
    for (int mf = 0; mf < 4; mf++)
#pragma unroll
      for (int j = 0; j < 4; j++) {
        const int gi = rbeg + m0 + wm + mf * 16 + rq + j;
        if (gi < rend) {
          const int slot = perm[gi];
          const float g = gates[slot];
          short* Cp = (short*)Cout + (size_t)slot * D_MODEL + bxn * 128 + wn + lr;
#pragma unroll
          for (int nf = 0; nf < 4; nf++) Cp[nf * 16] = f2b(g * acc[mf][nf][j]);
        }
      }
  } else {
    const float inv3 = 1.0f / 3.0f;
#pragma unroll
    for (int mf = 0; mf < 4; mf++)
#pragma unroll
      for (int j = 0; j < 4; j++) {
        const int tok = m_panel * 128 + wm + mf * 16 + rq + j;
        const int colb = n_panel * 128 + wn + lr;
        const short* y0p = yb + (size_t)(tok * 2) * D_MODEL + colb;
        const short* y1p = yb + (size_t)(tok * 2 + 1) * D_MODEL + colb;
        float* Op = (float*)Cout + (size_t)tok * D_MODEL + colb;
#pragma unroll
        for (int nf = 0; nf < 4; nf++) {
          Op[nf * 16] = (acc[mf][nf][j] + b2f(y0p[nf * 16]) + b2f(y1p[nf * 16])) * inv3;
        }
      }
  }
#undef STAGE
#undef LDA
#undef LDB
#undef MMROW
}

// ---------------- launch ----------------
extern "C" void kernel_launch(void* const* d_in, const int* in_sizes, int n_in,
                              void* d_out, int out_size, void* d_ws, size_t ws_size,
                              hipStream_t stream) {
  const float* x = (const float*)d_in[0];
  const float* temb = (const float*)d_in[1];
  const float* rw = (const float*)d_in[2];
  const float* rbias = (const float*)d_in[3];
  const float* w1 = (const float*)d_in[4];
  const float* w3 = (const float*)d_in[5];
  const float* w2 = (const float*)d_in[6];
  const float* W1e = (const float*)d_in[7];
  const float* W2e = (const float*)d_in[8];
  float* out = (float*)d_out;

  const size_t MB = 1ull << 20;
  char* w = (char*)d_ws;
  short* xb    = (short*)(w + 0 * MB);    // 8 MB  [4096][1024]
  short* w13I  = (short*)(w + 8 * MB);    // 8 MB  [4096][1024] interleaved w1/w3
  short* w2T   = (short*)(w + 16 * MB);   // 4 MB  [1024][2048]
  short* W1eT  = (short*)(w + 20 * MB);   // 16 MB [8][1024][1024]
  short* W2eT  = (short*)(w + 36 * MB);   // 16 MB [8][1024][1024]
  short* ubuf  = (short*)(w + 52 * MB);   // 16 MB [4096][2048]
  short* hexpb = (short*)(w + 68 * MB);   // 16 MB [8192][1024]
  short* yb    = (short*)(w + 84 * MB);   // 16 MB [8192][1024] gated bf16
  float* gates = (float*)(w + 100 * MB);  // 32 KB
  int* topk    = (int*)(w + 100 * MB + 32 * 1024);
  int* perm    = (int*)(w + 100 * MB + 64 * 1024);
  int* meta    = (int*)(w + 100 * MB + 96 * 1024);
  int* offs    = meta;           // 9 ints
  int* te      = meta + 16;      // <=72
  int* tm      = meta + 128;     // <=72
  int* ntile   = meta + 256;     // 1

  hipFuncSetAttribute((const void*)&g128<0, 16>,
                      hipFuncAttributeMaxDynamicSharedMemorySize, 65536);
  hipFuncSetAttribute((const void*)&g128<1, 16>,
                      hipFuncAttributeMaxDynamicSharedMemorySize, 65536);
  hipFuncSetAttribute((const void*)&g128<2, 16>,
                      hipFuncAttributeMaxDynamicSharedMemorySize, 65536);
  hipFuncSetAttribute((const void*)&g128<3, 32>,
                      hipFuncAttributeMaxDynamicSharedMemorySize, 65536);

  // prep
  tr_w13<<<dim3(HS / 64, D_MODEL / 64, 2), 256, 0, stream>>>(w1, w3, w13I);
  tr_w2<<<dim3(D_MODEL / 64, HS / 64, 1), 256, 0, stream>>>(w2, w2T);
  tr_exp<<<dim3(16, 16, 16), 256, 0, stream>>>(W1e, W2e, W1eT, W2eT);
  router_kernel<<<NTOK / 4, 256, 0, stream>>>(x, temb, rw, rbias, xb, topk, gates);
  group_kernel<<<1, 1024, 0, stream>>>(topk, perm, offs, te, tm, ntile);

  // G1: u = silu(x@w1)*(x@w3)  — 1024 blocks, 2/CU, 2 rounds
  g128<0, 16><<<1024, 256, 65536, stream>>>(xb, w13I, ubuf, nullptr, nullptr,
                                            nullptr, nullptr, nullptr, nullptr, nullptr);

  // routed experts — <=576 blocks, 2/CU
  g128<1, 16><<<576, 256, 65536, stream>>>(xb, W1eT, hexpb, perm, offs, gates,
                                           te, tm, ntile, nullptr);
  g128<2, 16><<<576, 256, 65536, stream>>>(hexpb, W2eT, yb, perm, offs, gates,
                                           te, tm, ntile, nullptr);

  // shared down-proj + final combine — 256 blocks
  g128<3, 32><<<256, 256, 65536, stream>>>(ubuf, w2T, out, nullptr, nullptr,
                                           nullptr, nullptr, nullptr, nullptr, yb);
}

// Round 14
// 210.820 us; speedup vs baseline: 1.0708x; 1.0708x over previous
//
#include <hip/hip_runtime.h>
#include <hip/hip_bf16.h>
#include <math.h>

#define D_MODEL 1024
#define HS 2048
#define HE 1024
#define NEXP 8
#define NTOK 4096
#define NSLOT 8192

typedef __attribute__((ext_vector_type(4))) float f32x4;
typedef __attribute__((ext_vector_type(8))) short bf16x8;

__device__ __forceinline__ short f2b(float f) {
  __hip_bfloat16 h = __float2bfloat16(f);
  return *reinterpret_cast<short*>(&h);
}
__device__ __forceinline__ float b2f(short s) {
  return __bfloat162float(*reinterpret_cast<__hip_bfloat16*>(&s));
}

__device__ __forceinline__ void gl_lds16(const short* g, short* l) {
  __builtin_amdgcn_global_load_lds(
      (const __attribute__((address_space(1))) void*)g,
      (__attribute__((address_space(3))) void*)l, 16, 0, 0);
}

// ---------------- merged transpose prep (one launch, 5632 blocks) ----------------
__device__ __forceinline__ void tr_tile(const float* __restrict__ in,
                                        short* __restrict__ out, int R, int C,
                                        int bx, int by, int bz, int rmap,
                                        float (*tile)[69], int t) {
  const int c0 = bx * 64;
  const int r0 = by * 64;
  const size_t bo = (size_t)bz * R * C;
  const int lr = t >> 4;
  const int lc4 = (t & 15) * 4;
#pragma unroll
  for (int i = 0; i < 4; i++) {
    const float4 v = *(const float4*)&in[bo + (size_t)(r0 + lr + i * 16) * C + c0 + lc4];
    tile[lc4 + 0][lr + i * 16] = v.x;
    tile[lc4 + 1][lr + i * 16] = v.y;
    tile[lc4 + 2][lr + i * 16] = v.z;
    tile[lc4 + 3][lr + i * 16] = v.w;
  }
  __syncthreads();
#pragma unroll
  for (int i = 0; i < 4; i++) {
    const int oc = (t >> 4) + i * 16;
    const int or4 = (t & 15) * 4;
    short4 o;
    o.x = f2b(tile[oc][or4 + 0]);
    o.y = f2b(tile[oc][or4 + 1]);
    o.z = f2b(tile[oc][or4 + 2]);
    o.w = f2b(tile[oc][or4 + 3]);
    const int c = c0 + oc;
    size_t orow;
    if (rmap == 0) orow = bo + (size_t)c * R;
    else orow = (size_t)((c >> 5) * 64 + (rmap == 2 ? 32 : 0) + (c & 31)) * R;
    *(short4*)&out[orow + r0 + or4] = o;
  }
}

__global__ __launch_bounds__(256) void tr_all(
    const float* __restrict__ w1, const float* __restrict__ w3,
    const float* __restrict__ w2, const float* __restrict__ W1e,
    const float* __restrict__ W2e, short* __restrict__ w13I,
    short* __restrict__ w2T, short* __restrict__ W1eT, short* __restrict__ W2eT) {
  __shared__ float tile[64][69];
  const int id = blockIdx.x;
  const int t = threadIdx.x;
  if (id < 1024) {  // w1/w3 -> w13I (interleaved)
    const int z = id >> 9, rem = id & 511;
    tr_tile(z ? w3 : w1, w13I, D_MODEL, HS, rem & 31, rem >> 5, 0, z ? 2 : 1, tile, t);
  } else if (id < 1536) {  // w2 -> w2T
    const int rem = id - 1024;
    tr_tile(w2, w2T, HS, D_MODEL, rem & 15, rem >> 4, 0, 0, tile, t);
  } else {  // experts
    const int rem = id - 1536;
    const int z = rem >> 8, r2 = rem & 255;
    if (z < 8)
      tr_tile(W1e, W1eT, D_MODEL, HE, r2 & 15, r2 >> 4, z, 0, tile, t);
    else
      tr_tile(W2e, W2eT, HE, D_MODEL, r2 & 15, r2 >> 4, z - 8, 0, tile, t);
  }
}

// ------- router + x->bf16 convert fused -------
__global__ __launch_bounds__(256) void router_kernel(
    const float* __restrict__ x, const float* __restrict__ temb,
    const float* __restrict__ rw, const float* __restrict__ rbias,
    short* __restrict__ xb, int* __restrict__ topk, float* __restrict__ gates) {
  const int t = (blockIdx.x * 256 + threadIdx.x) >> 6;
  const int lane = threadIdx.x & 63;
  const float* xr = x + (size_t)t * D_MODEL;
  const float* tr = temb + (size_t)(t >> 10) * D_MODEL;  // T=1024
  float acc[NEXP] = {};
#pragma unroll
  for (int i = 0; i < 4; i++) {
    const int j = i * 256 + lane * 4;
    const float4 xv = *(const float4*)&xr[j];
    const float4 tv = *(const float4*)&tr[j];
    short4 o;
    o.x = f2b(xv.x); o.y = f2b(xv.y); o.z = f2b(xv.z); o.w = f2b(xv.w);
    *(short4*)&xb[(size_t)t * D_MODEL + j] = o;
    const float* wx = rw + (size_t)j * NEXP;
    const float* wt = rw + (size_t)(D_MODEL + j) * NEXP;
    const float xa[4] = {xv.x, xv.y, xv.z, xv.w};
    const float ta[4] = {tv.x, tv.y, tv.z, tv.w};
#pragma unroll
    for (int u = 0; u < 4; u++)
#pragma unroll
      for (int e = 0; e < NEXP; e++)
        acc[e] += xa[u] * wx[u * NEXP + e] + ta[u] * wt[u * NEXP + e];
  }
#pragma unroll
  for (int off = 32; off; off >>= 1)
#pragma unroll
    for (int e = 0; e < NEXP; e++) acc[e] += __shfl_xor(acc[e], off);
  if (lane == 0) {
    float s[NEXP], sel[NEXP];
#pragma unroll
    for (int e = 0; e < NEXP; e++) {
      s[e] = 1.f / (1.f + expf(-acc[e]));
      sel[e] = s[e] + rbias[e];
    }
    int i0 = 0;
#pragma unroll
    for (int e = 1; e < NEXP; e++) if (sel[e] > sel[i0]) i0 = e;
    int i1 = (i0 == 0) ? 1 : 0;
#pragma unroll
    for (int e = 0; e < NEXP; e++) if (e != i0 && sel[e] > sel[i1]) i1 = e;
    float s0 = s[i0], s1 = s[i1], den = s0 + s1;
    float g0, g1;
    if (den > 1e-9f) { g0 = s0 / (den + 1e-9f); g1 = s1 / (den + 1e-9f); }
    else { g0 = 0.5f; g1 = 0.5f; }
    topk[t * 2] = i0; topk[t * 2 + 1] = i1;
    gates[t * 2] = g0; gates[t * 2 + 1] = g1;
  }
}

// ------- grouping: hist + scan + fill + BM=128 tile table (ntile <= 72) ------
__global__ __launch_bounds__(1024) void group_kernel(const int* __restrict__ topk,
                                                     int* __restrict__ perm,
                                                     int* __restrict__ offs,
                                                     int* __restrict__ te,
                                                     int* __restrict__ tm,
                                                     int* __restrict__ ntile) {
  __shared__ int cnt[NEXP], cur[NEXP];
  const int t = threadIdx.x;
  if (t < NEXP) cnt[t] = 0;
  __syncthreads();
  int mye[8];
#pragma unroll
  for (int i = 0; i < 8; i++) {
    mye[i] = topk[i * 1024 + t];
    atomicAdd(&cnt[mye[i]], 1);
  }
  __syncthreads();
  if (t == 0) {
    int a = 0;
    for (int e = 0; e < NEXP; e++) { offs[e] = a; cur[e] = a; a += cnt[e]; }
    offs[NEXP] = a;
    int nt = 0;
    for (int e = 0; e < NEXP; e++)
      for (int m0 = 0; m0 < cnt[e]; m0 += 128) { te[nt] = e; tm[nt] = m0; nt++; }
    ntile[0] = nt;  // <= 72
  }
  __syncthreads();
#pragma unroll
  for (int i = 0; i < 8; i++) {
    int pos = atomicAdd(&cur[mye[i]], 1);
    perm[pos] = i * 1024 + t;
  }
}

// ====== KERNEL-1: G1 (id<1024) || GG1 (id>=1024). 128² BK=32, 32KiB, 4 blk/CU ======
// R13 BUG FIX: G1 needs 32 B-panels (w13I has 4096 rows; 128 B-rows -> only
// 64 u-cols due to w1/w3 interleave), not 16. Grid 1024+576.
// LDS swizzle (64B rows): short_off = r*32 + 8*(kg ^ ((r>>2)&3)) — bijective;
// source col pre-swizzled to match (rule 21).
__global__ __launch_bounds__(256, 4) void moe_k1(
    const short* __restrict__ xb, const short* __restrict__ w13I,
    const short* __restrict__ W1eT, short* __restrict__ ubuf,
    short* __restrict__ hexpb, const int* __restrict__ perm,
    const int* __restrict__ offs, const int* __restrict__ te,
    const int* __restrict__ tm, const int* __restrict__ ntile) {
  extern __shared__ short lds[];
  const int td = threadIdx.x;
  const int id = blockIdx.x;
  const bool isG1 = id < 1024;
  int m_panel = 0, n_panel = 0, m0 = 0, rbeg = 0, rend = 0, bxn = 0;
  const short* A;
  const short* Bb;
  if (isG1) {
    const int xcd = id & 7, w = id >> 3;   // 128 blocks/XCD
    n_panel = xcd * 4 + (w >> 5);          // 0..31 (w13I_rows/128)
    m_panel = w & 31;                      // 0..31
    A = xb;
    Bb = w13I + (size_t)n_panel * 128 * 1024;
  } else {
    const int g = id - 1024;
    const int ty = g >> 3;
    if (ty >= ntile[0]) return;
    bxn = g & 7;
    const int e = te[ty];
    m0 = tm[ty];
    rbeg = offs[e]; rend = offs[e + 1];
    A = xb;
    Bb = W1eT + ((size_t)e * 1024 + bxn * 128) * 1024;
  }

  // staging pointers: row = td>>2 (+64), pre-swizzled col
  const int srow = td >> 2;                         // 0..63
  const int colsw = ((td & 3) ^ ((td >> 4) & 3)) * 8;
  const short* a0p;
  const short* a1p;
  {
    int g0, g1;
    if (isG1) { g0 = m_panel * 128 + srow; g1 = g0 + 64; }
    else {
      g0 = perm[min(rbeg + m0 + srow, rend - 1)] >> 1;
      g1 = perm[min(rbeg + m0 + 64 + srow, rend - 1)] >> 1;
    }
    a0p = A + (size_t)g0 * 1024 + colsw;
    a1p = A + (size_t)g1 * 1024 + colsw;
  }
  const short* b0p = Bb + (size_t)srow * 1024 + colsw;
  const short* b1p = Bb + (size_t)(64 + srow) * 1024 + colsw;

#define K1STAGE(t_, b_)                                             \
  do {                                                              \
    gl_lds16(a0p + (t_) * 32, lds + (b_) * 8192 + td * 8);          \
    gl_lds16(a1p + (t_) * 32, lds + (b_) * 8192 + 2048 + td * 8);   \
    gl_lds16(b0p + (t_) * 32, lds + (b_) * 8192 + 4096 + td * 8);   \
    gl_lds16(b1p + (t_) * 32, lds + (b_) * 8192 + 6144 + td * 8);   \
  } while (0)

  const int l = td & 63;
  const int wv = td >> 6;
  const int wm = (wv >> 1) * 64, wn = (wv & 1) * 64;
  const int lr = l & 15;
  const int kg = l >> 4;

#define SWO(r_) ((unsigned)((r_) * 32 + ((kg ^ (((r_) >> 2) & 3)) * 8)))
#define LDA1(mf_) (*(const bf16x8*)&Ah[SWO(wm + (mf_)*16 + lr)])
#define LDB1(nf_) (*(const bf16x8*)&Bh[SWO(wn + (nf_)*16 + lr)])
#define MM1(mf_, a_)                                                                   \
  acc[mf_][0] = __builtin_amdgcn_mfma_f32_16x16x32_bf16(a_, b0, acc[mf_][0], 0, 0, 0); \
  acc[mf_][1] = __builtin_amdgcn_mfma_f32_16x16x32_bf16(a_, b1, acc[mf_][1], 0, 0, 0); \
  acc[mf_][2] = __builtin_amdgcn_mfma_f32_16x16x32_bf16(a_, b2, acc[mf_][2], 0, 0, 0); \
  acc[mf_][3] = __builtin_amdgcn_mfma_f32_16x16x32_bf16(a_, b3, acc[mf_][3], 0, 0, 0)

  f32x4 acc[4][4] = {};

  K1STAGE(0, 0);
  for (int t = 0; t < 32; ++t) {
    const int p = t & 1, q = p ^ 1;
    const short* Ah = lds + p * 8192;
    const short* Bh = lds + p * 8192 + 4096;
    if (t < 31) {
      K1STAGE(t + 1, q);
      asm volatile("s_waitcnt vmcnt(4)" ::: "memory");
    } else {
      asm volatile("s_waitcnt vmcnt(0)" ::: "memory");
    }
    __builtin_amdgcn_s_barrier();
    {
      bf16x8 b0 = LDB1(0), b1 = LDB1(1), b2 = LDB1(2), b3 = LDB1(3);
      bf16x8 a0 = LDA1(0), a1 = LDA1(1), a2 = LDA1(2), a3 = LDA1(3);
      __builtin_amdgcn_s_setprio(1);
      MM1(0, a0); MM1(1, a1); MM1(2, a2); MM1(3, a3);
      __builtin_amdgcn_s_setprio(0);
    }
    __builtin_amdgcn_sched_barrier(0);
    __builtin_amdgcn_s_barrier();
  }

  const int rq = (l >> 4) * 4;
  if (isG1) {
#pragma unroll
    for (int mf = 0; mf < 4; mf++)
#pragma unroll
      for (int j = 0; j < 4; j++) {
        const int row = m_panel * 128 + wm + mf * 16 + rq + j;
        short* Up = ubuf + (size_t)row * HS + n_panel * 64 + (wn >> 1) + lr;
#pragma unroll
        for (int nf = 0; nf < 2; nf++) {
          const float a = acc[mf][nf][j];
          const float b = acc[mf][nf + 2][j];
          Up[nf * 16] = f2b(a / (1.f + expf(-a)) * b);
        }
      }
  } else {
#pragma unroll
    for (int mf = 0; mf < 4; mf++)
#pragma unroll
      for (int j = 0; j < 4; j++) {
        const int gi = rbeg + m0 + wm + mf * 16 + rq + j;
        if (gi < rend) {
          short* Cp = hexpb + (size_t)gi * HE + bxn * 128 + wn + lr;
#pragma unroll
          for (int nf = 0; nf < 4; nf++) {
            const float v = acc[mf][nf][j];
            Cp[nf * 16] = f2b(0.5f * v * (1.0f + erff(v * 0.70710678118654752f)));
          }
        }
      }
  }
#undef K1STAGE
#undef SWO
#undef LDA1
#undef LDB1
#undef MM1
}

// ====== KERNEL-2: G2 (id<256, K=2048->out f32) || GG2 (id>=256, K=1024->yb) ======
// R12-proven 128² BK=64 counted-2-barrier template, 64KiB, 2 blk/CU.
__global__ __launch_bounds__(256, 2) void moe_k2(
    const short* __restrict__ ubuf, const short* __restrict__ w2T,
    const short* __restrict__ hexpb, const short* __restrict__ W2eT,
    float* __restrict__ out, short* __restrict__ yb,
    const int* __restrict__ perm, const int* __restrict__ offs,
    const float* __restrict__ gates, const int* __restrict__ te,
    const int* __restrict__ tm, const int* __restrict__ ntile) {
  extern __shared__ short lds[];
  const int td = threadIdx.x;
  const int id = blockIdx.x;
  const bool isG2 = id < 256;
  int m_panel = 0, n_panel = 0, m0 = 0, rbeg = 0, rend = 0, bxn = 0, NT, K;
  const short* A;
  const short* Bb;
  if (isG2) {
    const int xcd = id & 7, slot = id >> 3;
    n_panel = slot & 7;               // D_MODEL/128
    m_panel = xcd * 4 + (slot >> 3);  // 32 panels
    A = ubuf;
    K = HS; NT = 32;
    Bb = w2T + (size_t)n_panel * 128 * HS;
  } else {
    const int g = id - 256;
    const int ty = g >> 3;
    if (ty >= ntile[0]) return;
    bxn = g & 7;
    const int e = te[ty];
    m0 = tm[ty];
    rbeg = offs[e]; rend = offs[e + 1];
    A = hexpb;
    K = HE; NT = 16;
    Bb = W2eT + ((size_t)e * 1024 + bxn * 128) * 1024;
  }

  const int srow = td >> 3;  // 0..31
  const int colsw8 = ((td & 7) ^ (srow & 7)) * 8;
  const short* ap[4];
  const short* bp[4];
#pragma unroll
  for (int u = 0; u < 4; u++) {
    const int trow = u * 32 + srow;
    int grow;
    if (isG2) grow = m_panel * 128 + trow;
    else grow = min(rbeg + m0 + trow, rend - 1);
    ap[u] = A + (size_t)grow * K + colsw8;
    bp[u] = Bb + (size_t)trow * K + colsw8;
  }

#define K2STAGE(t_, b_)                                                    \
  do {                                                                     \
    gl_lds16(ap[0] + (t_) * 64, lds + (b_) * 16384 + td * 8);              \
    gl_lds16(ap[1] + (t_) * 64, lds + (b_) * 16384 + 2048 + td * 8);       \
    gl_lds16(ap[2] + (t_) * 64, lds + (b_) * 16384 + 4096 + td * 8);       \
    gl_lds16(ap[3] + (t_) * 64, lds + (b_) * 16384 + 6144 + td * 8);       \
    gl_lds16(bp[0] + (t_) * 64, lds + (b_) * 16384 + 8192 + td * 8);       \
    gl_lds16(bp[1] + (t_) * 64, lds + (b_) * 16384 + 10240 + td * 8);      \
    gl_lds16(bp[2] + (t_) * 64, lds + (b_) * 16384 + 12288 + td * 8);      \
    gl_lds16(bp[3] + (t_) * 64, lds + (b_) * 16384 + 14336 + td * 8);      \
  } while (0)

  const int l = td & 63;
  const int wv = td >> 6;
  const int wm = (wv >> 1) * 64, wn = (wv & 1) * 64;
  const int lr = l & 15;
  const int swzk0 = ((0 + (l >> 4) * 16) ^ ((l & 7) << 4)) >> 1;
  const int swzk1 = ((64 + (l >> 4) * 16) ^ ((l & 7) << 4)) >> 1;

#define LDA2(mf_, swz_) (*(const bf16x8*)&Ah[(unsigned)(((mf_)*16 + lr) * 64) + (swz_)])
#define LDB2(nf_, swz_) (*(const bf16x8*)&Bh[(unsigned)(((nf_)*16 + lr) * 64) + (swz_)])
#define MM2(mf_, a_)                                                                   \
  acc[mf_][0] = __builtin_amdgcn_mfma_f32_16x16x32_bf16(a_, b0, acc[mf_][0], 0, 0, 0); \
  acc[mf_][1] = __builtin_amdgcn_mfma_f32_16x16x32_bf16(a_, b1, acc[mf_][1], 0, 0, 0); \
  acc[mf_][2] = __builtin_amdgcn_mfma_f32_16x16x32_bf16(a_, b2, acc[mf_][2], 0, 0, 0); \
  acc[mf_][3] = __builtin_amdgcn_mfma_f32_16x16x32_bf16(a_, b3, acc[mf_][3], 0, 0, 0)

  f32x4 acc[4][4] = {};

  K2STAGE(0, 0);
  for (int t = 0; t < NT; ++t) {
    const int p = t & 1, q = p ^ 1;
    const short* Ah = lds + p * 16384 + wm * 64;
    const short* Bh = lds + p * 16384 + 8192 + wn * 64;
    if (t < NT - 1) {
      K2STAGE(t + 1, q);
      asm volatile("s_waitcnt vmcnt(8)" ::: "memory");
    } else {
      asm volatile("s_waitcnt vmcnt(0)" ::: "memory");
    }
    __builtin_amdgcn_s_barrier();
    {
      bf16x8 b0, b1, b2, b3, a0, a1, a2, a3;
      b0 = LDB2(0, swzk0); b1 = LDB2(1, swzk0); b2 = LDB2(2, swzk0); b3 = LDB2(3, swzk0);
      a0 = LDA2(0, swzk0); a1 = LDA2(1, swzk0); a2 = LDA2(2, swzk0); a3 = LDA2(3, swzk0);
      __builtin_amdgcn_s_setprio(1);
      MM2(0, a0); MM2(1, a1); MM2(2, a2); MM2(3, a3);
      __builtin_amdgcn_s_setprio(0);
      b0 = LDB2(0, swzk1); b1 = LDB2(1, swzk1); b2 = LDB2(2, swzk1); b3 = LDB2(3, swzk1);
      a0 = LDA2(0, swzk1); a1 = LDA2(1, swzk1); a2 = LDA2(2, swzk1); a3 = LDA2(3, swzk1);
      __builtin_amdgcn_s_setprio(1);
      MM2(0, a0); MM2(1, a1); MM2(2, a2); MM2(3, a3);
      __builtin_amdgcn_s_setprio(0);
    }
    __builtin_amdgcn_sched_barrier(0);
    __builtin_amdgcn_s_barrier();
  }

  const int rq = (l >> 4) * 4;
  if (isG2) {
#pragma unroll
    for (int mf = 0; mf < 4; mf++)
#pragma unroll
      for (int j = 0; j < 4; j++) {
        const int tok = m_panel * 128 + wm + mf * 16 + rq + j;
        float* Op = out + (size_t)tok * D_MODEL + n_panel * 128 + wn + lr;
#pragma unroll
        for (int nf = 0; nf < 4; nf++) Op[nf * 16] = acc[mf][nf][j];
      }
  } else {
#pragma unroll
    for (int mf = 0; mf < 4; mf++)
#pragma unroll
      for (int j = 0; j < 4; j++) {
        const int gi = rbeg + m0 + wm + mf * 16 + rq + j;
        if (gi < rend) {
          const int slot = perm[gi];
          const float g = gates[slot];
          short* Cp = yb + (size_t)slot * D_MODEL + bxn * 128 + wn + lr;
#pragma unroll
          for (int nf = 0; nf < 4; nf++) Cp[nf * 16] = f2b(g * acc[mf][nf][j]);
        }
      }
  }
#undef K2STAGE
#undef LDA2
#undef LDB2
#undef MM2
}

// ---- final combine: out = (out(shared) + y0 + y1) / 3 ----
__global__ __launch_bounds__(256) void combine_kernel(float* __restrict__ out,
                                                      const short* __restrict__ yb) {
  const float inv3 = 1.0f / 3.0f;
#pragma unroll
  for (int rep = 0; rep < 2; rep++) {
    const int i = (rep * 2048 + blockIdx.x) * 256 + threadIdx.x;  // float4 index
    const int base = i * 4;
    const int tok = base >> 10;
    const int col = base & (D_MODEL - 1);
    float4 s = *(float4*)&out[base];
    const short4 y0 = *(const short4*)&yb[(size_t)(tok * 2) * D_MODEL + col];
    const short4 y1 = *(const short4*)&yb[(size_t)(tok * 2 + 1) * D_MODEL + col];
    s.x = (s.x + b2f(y0.x) + b2f(y1.x)) * inv3;
    s.y = (s.y + b2f(y0.y) + b2f(y1.y)) * inv3;
    s.z = (s.z + b2f(y0.z) + b2f(y1.z)) * inv3;
    s.w = (s.w + b2f(y0.w) + b2f(y1.w)) * inv3;
    *(float4*)&out[base] = s;
  }
}

// ---------------- launch ----------------
extern "C" void kernel_launch(void* const* d_in, const int* in_sizes, int n_in,
                              void* d_out, int out_size, void* d_ws, size_t ws_size,
                              hipStream_t stream) {
  const float* x = (const float*)d_in[0];
  const float* temb = (const float*)d_in[1];
  const float* rw = (const float*)d_in[2];
  const float* rbias = (const float*)d_in[3];
  const float* w1 = (const float*)d_in[4];
  const float* w3 = (const float*)d_in[5];
  const float* w2 = (const float*)d_in[6];
  const float* W1e = (const float*)d_in[7];
  const float* W2e = (const float*)d_in[8];
  float* out = (float*)d_out;

  const size_t MB = 1ull << 20;
  char* w = (char*)d_ws;
  short* xb    = (short*)(w + 0 * MB);
  short* w13I  = (short*)(w + 8 * MB);
  short* w2T   = (short*)(w + 16 * MB);
  short* W1eT  = (short*)(w + 20 * MB);
  short* W2eT  = (short*)(w + 36 * MB);
  short* ubuf  = (short*)(w + 52 * MB);
  short* hexpb = (short*)(w + 68 * MB);
  short* yb    = (short*)(w + 84 * MB);
  float* gates = (float*)(w + 100 * MB);
  int* topk    = (int*)(w + 100 * MB + 32 * 1024);
  int* perm    = (int*)(w + 100 * MB + 64 * 1024);
  int* meta    = (int*)(w + 100 * MB + 96 * 1024);
  int* offs    = meta;
  int* te      = meta + 16;
  int* tm      = meta + 128;
  int* ntile   = meta + 256;

  hipFuncSetAttribute((const void*)&moe_k1,
                      hipFuncAttributeMaxDynamicSharedMemorySize, 32768);
  hipFuncSetAttribute((const void*)&moe_k2,
                      hipFuncAttributeMaxDynamicSharedMemorySize, 65536);

  // prep
  tr_all<<<5632, 256, 0, stream>>>(w1, w3, w2, W1e, W2e, w13I, w2T, W1eT, W2eT);
  router_kernel<<<NTOK / 4, 256, 0, stream>>>(x, temb, rw, rbias, xb, topk, gates);
  group_kernel<<<1, 1024, 0, stream>>>(topk, perm, offs, te, tm, ntile);

  // kernel-1: G1 (1024 blocks) || GG1 (576 blocks), 4 blocks/CU
  moe_k1<<<1600, 256, 32768, stream>>>(xb, w13I, W1eT, ubuf, hexpb, perm, offs,
                                       te, tm, ntile);

  // kernel-2: G2 (256, -> out f32) || GG2 (576, -> yb), 2 blocks/CU
  moe_k2<<<832, 256, 65536, stream>>>(ubuf, w2T, hexpb, W2eT, out, yb, perm,
                                      offs, gates, te, tm, ntile);

  // combine
  combine_kernel<<<2048, 256, 0, stream>>>(out, yb);
}

// Round 15
// 210.109 us; speedup vs baseline: 1.0744x; 1.0034x over previous
//
#include <hip/hip_runtime.h>
#include <hip/hip_bf16.h>
#include <math.h>

#define D_MODEL 1024
#define HS 2048
#define HE 1024
#define NEXP 8
#define NTOK 4096
#define NSLOT 8192

typedef __attribute__((ext_vector_type(4))) float f32x4;
typedef __attribute__((ext_vector_type(8))) short bf16x8;

__device__ __forceinline__ short f2b(float f) {
  __hip_bfloat16 h = __float2bfloat16(f);
  return *reinterpret_cast<short*>(&h);
}
__device__ __forceinline__ float b2f(short s) {
  return __bfloat162float(*reinterpret_cast<__hip_bfloat16*>(&s));
}

__device__ __forceinline__ void gl_lds16(const short* g, short* l) {
  __builtin_amdgcn_global_load_lds(
      (const __attribute__((address_space(1))) void*)g,
      (__attribute__((address_space(3))) void*)l, 16, 0, 0);
}

// ---------------- merged transpose prep (one launch, 5632 blocks) ----------------
__device__ __forceinline__ void tr_tile(const float* __restrict__ in,
                                        short* __restrict__ out, int R, int C,
                                        int bx, int by, int bz, int rmap,
                                        float (*tile)[69], int t) {
  const int c0 = bx * 64;
  const int r0 = by * 64;
  const size_t bo = (size_t)bz * R * C;
  const int lr = t >> 4;
  const int lc4 = (t & 15) * 4;
#pragma unroll
  for (int i = 0; i < 4; i++) {
    const float4 v = *(const float4*)&in[bo + (size_t)(r0 + lr + i * 16) * C + c0 + lc4];
    tile[lc4 + 0][lr + i * 16] = v.x;
    tile[lc4 + 1][lr + i * 16] = v.y;
    tile[lc4 + 2][lr + i * 16] = v.z;
    tile[lc4 + 3][lr + i * 16] = v.w;
  }
  __syncthreads();
#pragma unroll
  for (int i = 0; i < 4; i++) {
    const int oc = (t >> 4) + i * 16;
    const int or4 = (t & 15) * 4;
    short4 o;
    o.x = f2b(tile[oc][or4 + 0]);
    o.y = f2b(tile[oc][or4 + 1]);
    o.z = f2b(tile[oc][or4 + 2]);
    o.w = f2b(tile[oc][or4 + 3]);
    const int c = c0 + oc;
    size_t orow;
    if (rmap == 0) orow = bo + (size_t)c * R;
    else orow = (size_t)((c >> 5) * 64 + (rmap == 2 ? 32 : 0) + (c & 31)) * R;
    *(short4*)&out[orow + r0 + or4] = o;
  }
}

__global__ __launch_bounds__(256) void tr_all(
    const float* __restrict__ w1, const float* __restrict__ w3,
    const float* __restrict__ w2, const float* __restrict__ W1e,
    const float* __restrict__ W2e, short* __restrict__ w13I,
    short* __restrict__ w2T, short* __restrict__ W1eT, short* __restrict__ W2eT) {
  __shared__ float tile[64][69];
  const int id = blockIdx.x;
  const int t = threadIdx.x;
  if (id < 1024) {  // w1/w3 -> w13I (interleaved)
    const int z = id >> 9, rem = id & 511;
    tr_tile(z ? w3 : w1, w13I, D_MODEL, HS, rem & 31, rem >> 5, 0, z ? 2 : 1, tile, t);
  } else if (id < 1536) {  // w2 -> w2T
    const int rem = id - 1024;
    tr_tile(w2, w2T, HS, D_MODEL, rem & 15, rem >> 4, 0, 0, tile, t);
  } else {  // experts
    const int rem = id - 1536;
    const int z = rem >> 8, r2 = rem & 255;
    if (z < 8)
      tr_tile(W1e, W1eT, D_MODEL, HE, r2 & 15, r2 >> 4, z, 0, tile, t);
    else
      tr_tile(W2e, W2eT, HE, D_MODEL, r2 & 15, r2 >> 4, z - 8, 0, tile, t);
  }
}

// ------- router + x->bf16 convert fused -------
__global__ __launch_bounds__(256) void router_kernel(
    const float* __restrict__ x, const float* __restrict__ temb,
    const float* __restrict__ rw, const float* __restrict__ rbias,
    short* __restrict__ xb, int* __restrict__ topk, float* __restrict__ gates) {
  const int t = (blockIdx.x * 256 + threadIdx.x) >> 6;
  const int lane = threadIdx.x & 63;
  const float* xr = x + (size_t)t * D_MODEL;
  const float* tr = temb + (size_t)(t >> 10) * D_MODEL;  // T=1024
  float acc[NEXP] = {};
#pragma unroll
  for (int i = 0; i < 4; i++) {
    const int j = i * 256 + lane * 4;
    const float4 xv = *(const float4*)&xr[j];
    const float4 tv = *(const float4*)&tr[j];
    short4 o;
    o.x = f2b(xv.x); o.y = f2b(xv.y); o.z = f2b(xv.z); o.w = f2b(xv.w);
    *(short4*)&xb[(size_t)t * D_MODEL + j] = o;
    const float* wx = rw + (size_t)j * NEXP;
    const float* wt = rw + (size_t)(D_MODEL + j) * NEXP;
    const float xa[4] = {xv.x, xv.y, xv.z, xv.w};
    const float ta[4] = {tv.x, tv.y, tv.z, tv.w};
#pragma unroll
    for (int u = 0; u < 4; u++)
#pragma unroll
      for (int e = 0; e < NEXP; e++)
        acc[e] += xa[u] * wx[u * NEXP + e] + ta[u] * wt[u * NEXP + e];
  }
#pragma unroll
  for (int off = 32; off; off >>= 1)
#pragma unroll
    for (int e = 0; e < NEXP; e++) acc[e] += __shfl_xor(acc[e], off);
  if (lane == 0) {
    float s[NEXP], sel[NEXP];
#pragma unroll
    for (int e = 0; e < NEXP; e++) {
      s[e] = 1.f / (1.f + expf(-acc[e]));
      sel[e] = s[e] + rbias[e];
    }
    int i0 = 0;
#pragma unroll
    for (int e = 1; e < NEXP; e++) if (sel[e] > sel[i0]) i0 = e;
    int i1 = (i0 == 0) ? 1 : 0;
#pragma unroll
    for (int e = 0; e < NEXP; e++) if (e != i0 && sel[e] > sel[i1]) i1 = e;
    float s0 = s[i0], s1 = s[i1], den = s0 + s1;
    float g0, g1;
    if (den > 1e-9f) { g0 = s0 / (den + 1e-9f); g1 = s1 / (den + 1e-9f); }
    else { g0 = 0.5f; g1 = 0.5f; }
    topk[t * 2] = i0; topk[t * 2 + 1] = i1;
    gates[t * 2] = g0; gates[t * 2 + 1] = g1;
  }
}

// ------- grouping: hist + scan + fill + BM=128 tile table (ntile <= 72) ------
__global__ __launch_bounds__(1024) void group_kernel(const int* __restrict__ topk,
                                                     int* __restrict__ perm,
                                                     int* __restrict__ offs,
                                                     int* __restrict__ te,
                                                     int* __restrict__ tm,
                                                     int* __restrict__ ntile) {
  __shared__ int cnt[NEXP], cur[NEXP];
  const int t = threadIdx.x;
  if (t < NEXP) cnt[t] = 0;
  __syncthreads();
  int mye[8];
#pragma unroll
  for (int i = 0; i < 8; i++) {
    mye[i] = topk[i * 1024 + t];
    atomicAdd(&cnt[mye[i]], 1);
  }
  __syncthreads();
  if (t == 0) {
    int a = 0;
    for (int e = 0; e < NEXP; e++) { offs[e] = a; cur[e] = a; a += cnt[e]; }
    offs[NEXP] = a;
    int nt = 0;
    for (int e = 0; e < NEXP; e++)
      for (int m0 = 0; m0 < cnt[e]; m0 += 128) { te[nt] = e; tm[nt] = m0; nt++; }
    ntile[0] = nt;  // <= 72
  }
  __syncthreads();
#pragma unroll
  for (int i = 0; i < 8; i++) {
    int pos = atomicAdd(&cur[mye[i]], 1);
    perm[pos] = i * 1024 + t;
  }
}

// ====== KERNEL-1: G1 (id<1024) || GG1 (id>=1024) ======
// R15: ported to the PROVEN k2 template (BK=64, 64KiB LDS, conc-2, zero-
// conflict swizzle). R14's BK=32/conc-4 variant had 6.45M bank conflicts and
// half the MFMA-per-barrier -> 600 TF vs template's 764.
__global__ __launch_bounds__(256, 2) void moe_k1(
    const short* __restrict__ xb, const short* __restrict__ w13I,
    const short* __restrict__ W1eT, short* __restrict__ ubuf,
    short* __restrict__ hexpb, const int* __restrict__ perm,
    const int* __restrict__ offs, const int* __restrict__ te,
    const int* __restrict__ tm, const int* __restrict__ ntile) {
  extern __shared__ short lds[];
  const int td = threadIdx.x;
  const int id = blockIdx.x;
  const bool isG1 = id < 1024;
  int m_panel = 0, n_panel = 0, m0 = 0, rbeg = 0, rend = 0, bxn = 0;
  const short* A;
  const short* Bb;
  if (isG1) {
    const int xcd = id & 7, w = id >> 3;   // 128 blocks/XCD
    n_panel = xcd * 4 + (w >> 5);          // 0..31 (w13I 4096 rows / 128)
    m_panel = w & 31;                      // 0..31
    A = xb;
    Bb = w13I + (size_t)n_panel * 128 * 1024;
  } else {
    const int g = id - 1024;
    const int ty = g >> 3;
    if (ty >= ntile[0]) return;
    bxn = g & 7;
    const int e = te[ty];
    m0 = tm[ty];
    rbeg = offs[e]; rend = offs[e + 1];
    A = xb;
    Bb = W1eT + ((size_t)e * 1024 + bxn * 128) * 1024;
  }

  const int srow = td >> 3;  // 0..31
  const int colsw8 = ((td & 7) ^ (srow & 7)) * 8;
  const short* ap[4];
  const short* bp[4];
#pragma unroll
  for (int u = 0; u < 4; u++) {
    const int trow = u * 32 + srow;
    int grow;
    if (isG1) grow = m_panel * 128 + trow;
    else grow = perm[min(rbeg + m0 + trow, rend - 1)] >> 1;
    ap[u] = A + (size_t)grow * 1024 + colsw8;
    bp[u] = Bb + (size_t)trow * 1024 + colsw8;
  }

#define K1STAGE(t_, b_)                                                    \
  do {                                                                     \
    gl_lds16(ap[0] + (t_) * 64, lds + (b_) * 16384 + td * 8);              \
    gl_lds16(ap[1] + (t_) * 64, lds + (b_) * 16384 + 2048 + td * 8);       \
    gl_lds16(ap[2] + (t_) * 64, lds + (b_) * 16384 + 4096 + td * 8);       \
    gl_lds16(ap[3] + (t_) * 64, lds + (b_) * 16384 + 6144 + td * 8);       \
    gl_lds16(bp[0] + (t_) * 64, lds + (b_) * 16384 + 8192 + td * 8);       \
    gl_lds16(bp[1] + (t_) * 64, lds + (b_) * 16384 + 10240 + td * 8);      \
    gl_lds16(bp[2] + (t_) * 64, lds + (b_) * 16384 + 12288 + td * 8);      \
    gl_lds16(bp[3] + (t_) * 64, lds + (b_) * 16384 + 14336 + td * 8);      \
  } while (0)

  const int l = td & 63;
  const int wv = td >> 6;
  const int wm = (wv >> 1) * 64, wn = (wv & 1) * 64;
  const int lr = l & 15;
  const int swzk0 = ((0 + (l >> 4) * 16) ^ ((l & 7) << 4)) >> 1;
  const int swzk1 = ((64 + (l >> 4) * 16) ^ ((l & 7) << 4)) >> 1;

#define LDA1(mf_, swz_) (*(const bf16x8*)&Ah[(unsigned)(((mf_)*16 + lr) * 64) + (swz_)])
#define LDB1(nf_, swz_) (*(const bf16x8*)&Bh[(unsigned)(((nf_)*16 + lr) * 64) + (swz_)])
#define MM1(mf_, a_)                                                                   \
  acc[mf_][0] = __builtin_amdgcn_mfma_f32_16x16x32_bf16(a_, b0, acc[mf_][0], 0, 0, 0); \
  acc[mf_][1] = __builtin_amdgcn_mfma_f32_16x16x32_bf16(a_, b1, acc[mf_][1], 0, 0, 0); \
  acc[mf_][2] = __builtin_amdgcn_mfma_f32_16x16x32_bf16(a_, b2, acc[mf_][2], 0, 0, 0); \
  acc[mf_][3] = __builtin_amdgcn_mfma_f32_16x16x32_bf16(a_, b3, acc[mf_][3], 0, 0, 0)

  f32x4 acc[4][4] = {};

  K1STAGE(0, 0);
  for (int t = 0; t < 16; ++t) {
    const int p = t & 1, q = p ^ 1;
    const short* Ah = lds + p * 16384 + wm * 64;
    const short* Bh = lds + p * 16384 + 8192 + wn * 64;
    if (t < 15) {
      K1STAGE(t + 1, q);
      asm volatile("s_waitcnt vmcnt(8)" ::: "memory");
    } else {
      asm volatile("s_waitcnt vmcnt(0)" ::: "memory");
    }
    __builtin_amdgcn_s_barrier();
    {
      bf16x8 b0, b1, b2, b3, a0, a1, a2, a3;
      b0 = LDB1(0, swzk0); b1 = LDB1(1, swzk0); b2 = LDB1(2, swzk0); b3 = LDB1(3, swzk0);
      a0 = LDA1(0, swzk0); a1 = LDA1(1, swzk0); a2 = LDA1(2, swzk0); a3 = LDA1(3, swzk0);
      __builtin_amdgcn_s_setprio(1);
      MM1(0, a0); MM1(1, a1); MM1(2, a2); MM1(3, a3);
      __builtin_amdgcn_s_setprio(0);
      b0 = LDB1(0, swzk1); b1 = LDB1(1, swzk1); b2 = LDB1(2, swzk1); b3 = LDB1(3, swzk1);
      a0 = LDA1(0, swzk1); a1 = LDA1(1, swzk1); a2 = LDA1(2, swzk1); a3 = LDA1(3, swzk1);
      __builtin_amdgcn_s_setprio(1);
      MM1(0, a0); MM1(1, a1); MM1(2, a2); MM1(3, a3);
      __builtin_amdgcn_s_setprio(0);
    }
    __builtin_amdgcn_sched_barrier(0);
    __builtin_amdgcn_s_barrier();
  }

  const int rq = (l >> 4) * 4;
  if (isG1) {
#pragma unroll
    for (int mf = 0; mf < 4; mf++)
#pragma unroll
      for (int j = 0; j < 4; j++) {
        const int row = m_panel * 128 + wm + mf * 16 + rq + j;
        short* Up = ubuf + (size_t)row * HS + n_panel * 64 + (wn >> 1) + lr;
#pragma unroll
        for (int nf = 0; nf < 2; nf++) {
          const float a = acc[mf][nf][j];
          const float b = acc[mf][nf + 2][j];
          Up[nf * 16] = f2b(a / (1.f + expf(-a)) * b);
        }
      }
  } else {
#pragma unroll
    for (int mf = 0; mf < 4; mf++)
#pragma unroll
      for (int j = 0; j < 4; j++) {
        const int gi = rbeg + m0 + wm + mf * 16 + rq + j;
        if (gi < rend) {
          short* Cp = hexpb + (size_t)gi * HE + bxn * 128 + wn + lr;
#pragma unroll
          for (int nf = 0; nf < 4; nf++) {
            const float v = acc[mf][nf][j];
            Cp[nf * 16] = f2b(0.5f * v * (1.0f + erff(v * 0.70710678118654752f)));
          }
        }
      }
  }
#undef K1STAGE
#undef LDA1
#undef LDB1
#undef MM1
}

// ====== KERNEL-2: G2 (id<256, K=2048->out f32) || GG2 (id>=256, K=1024->yb) ======
// R12-proven 128² BK=64 counted-2-barrier template, 64KiB, 2 blk/CU.
__global__ __launch_bounds__(256, 2) void moe_k2(
    const short* __restrict__ ubuf, const short* __restrict__ w2T,
    const short* __restrict__ hexpb, const short* __restrict__ W2eT,
    float* __restrict__ out, short* __restrict__ yb,
    const int* __restrict__ perm, const int* __restrict__ offs,
    const float* __restrict__ gates, const int* __restrict__ te,
    const int* __restrict__ tm, const int* __restrict__ ntile) {
  extern __shared__ short lds[];
  const int td = threadIdx.x;
  const int id = blockIdx.x;
  const bool isG2 = id < 256;
  int m_panel = 0, n_panel = 0, m0 = 0, rbeg = 0, rend = 0, bxn = 0, NT, K;
  const short* A;
  const short* Bb;
  if (isG2) {
    const int xcd = id & 7, slot = id >> 3;
    n_panel = slot & 7;               // D_MODEL/128
    m_panel = xcd * 4 + (slot >> 3);  // 32 panels
    A = ubuf;
    K = HS; NT = 32;
    Bb = w2T + (size_t)n_panel * 128 * HS;
  } else {
    const int g = id - 256;
    const int ty = g >> 3;
    if (ty >= ntile[0]) return;
    bxn = g & 7;
    const int e = te[ty];
    m0 = tm[ty];
    rbeg = offs[e]; rend = offs[e + 1];
    A = hexpb;
    K = HE; NT = 16;
    Bb = W2eT + ((size_t)e * 1024 + bxn * 128) * 1024;
  }

  const int srow = td >> 3;  // 0..31
  const int colsw8 = ((td & 7) ^ (srow & 7)) * 8;
  const short* ap[4];
  const short* bp[4];
#pragma unroll
  for (int u = 0; u < 4; u++) {
    const int trow = u * 32 + srow;
    int grow;
    if (isG2) grow = m_panel * 128 + trow;
    else grow = min(rbeg + m0 + trow, rend - 1);
    ap[u] = A + (size_t)grow * K + colsw8;
    bp[u] = Bb + (size_t)trow * K + colsw8;
  }

#define K2STAGE(t_, b_)                                                    \
  do {                                                                     \
    gl_lds16(ap[0] + (t_) * 64, lds + (b_) * 16384 + td * 8);              \
    gl_lds16(ap[1] + (t_) * 64, lds + (b_) * 16384 + 2048 + td * 8);       \
    gl_lds16(ap[2] + (t_) * 64, lds + (b_) * 16384 + 4096 + td * 8);       \
    gl_lds16(ap[3] + (t_) * 64, lds + (b_) * 16384 + 6144 + td * 8);       \
    gl_lds16(bp[0] + (t_) * 64, lds + (b_) * 16384 + 8192 + td * 8);       \
    gl_lds16(bp[1] + (t_) * 64, lds + (b_) * 16384 + 10240 + td * 8);      \
    gl_lds16(bp[2] + (t_) * 64, lds + (b_) * 16384 + 12288 + td * 8);      \
    gl_lds16(bp[3] + (t_) * 64, lds + (b_) * 16384 + 14336 + td * 8);      \
  } while (0)

  const int l = td & 63;
  const int wv = td >> 6;
  const int wm = (wv >> 1) * 64, wn = (wv & 1) * 64;
  const int lr = l & 15;
  const int swzk0 = ((0 + (l >> 4) * 16) ^ ((l & 7) << 4)) >> 1;
  const int swzk1 = ((64 + (l >> 4) * 16) ^ ((l & 7) << 4)) >> 1;

#define LDA2(mf_, swz_) (*(const bf16x8*)&Ah[(unsigned)(((mf_)*16 + lr) * 64) + (swz_)])
#define LDB2(nf_, swz_) (*(const bf16x8*)&Bh[(unsigned)(((nf_)*16 + lr) * 64) + (swz_)])
#define MM2(mf_, a_)                                                                   \
  acc[mf_][0] = __builtin_amdgcn_mfma_f32_16x16x32_bf16(a_, b0, acc[mf_][0], 0, 0, 0); \
  acc[mf_][1] = __builtin_amdgcn_mfma_f32_16x16x32_bf16(a_, b1, acc[mf_][1], 0, 0, 0); \
  acc[mf_][2] = __builtin_amdgcn_mfma_f32_16x16x32_bf16(a_, b2, acc[mf_][2], 0, 0, 0); \
  acc[mf_][3] = __builtin_amdgcn_mfma_f32_16x16x32_bf16(a_, b3, acc[mf_][3], 0, 0, 0)

  f32x4 acc[4][4] = {};

  K2STAGE(0, 0);
  for (int t = 0; t < NT; ++t) {
    const int p = t & 1, q = p ^ 1;
    const short* Ah = lds + p * 16384 + wm * 64;
    const short* Bh = lds + p * 16384 + 8192 + wn * 64;
    if (t < NT - 1) {
      K2STAGE(t + 1, q);
      asm volatile("s_waitcnt vmcnt(8)" ::: "memory");
    } else {
      asm volatile("s_waitcnt vmcnt(0)" ::: "memory");
    }
    __builtin_amdgcn_s_barrier();
    {
      bf16x8 b0, b1, b2, b3, a0, a1, a2, a3;
      b0 = LDB2(0, swzk0); b1 = LDB2(1, swzk0); b2 = LDB2(2, swzk0); b3 = LDB2(3, swzk0);
      a0 = LDA2(0, swzk0); a1 = LDA2(1, swzk0); a2 = LDA2(2, swzk0); a3 = LDA2(3, swzk0);
      __builtin_amdgcn_s_setprio(1);
      MM2(0, a0); MM2(1, a1); MM2(2, a2); MM2(3, a3);
      __builtin_amdgcn_s_setprio(0);
      b0 = LDB2(0, swzk1); b1 = LDB2(1, swzk1); b2 = LDB2(2, swzk1); b3 = LDB2(3, swzk1);
      a0 = LDA2(0, swzk1); a1 = LDA2(1, swzk1); a2 = LDA2(2, swzk1); a3 = LDA2(3, swzk1);
      __builtin_amdgcn_s_setprio(1);
      MM2(0, a0); MM2(1, a1); MM2(2, a2); MM2(3, a3);
      __builtin_amdgcn_s_setprio(0);
    }
    __builtin_amdgcn_sched_barrier(0);
    __builtin_amdgcn_s_barrier();
  }

  const int rq = (l >> 4) * 4;
  if (isG2) {
#pragma unroll
    for (int mf = 0; mf < 4; mf++)
#pragma unroll
      for (int j = 0; j < 4; j++) {
        const int tok = m_panel * 128 + wm + mf * 16 + rq + j;
        float* Op = out + (size_t)tok * D_MODEL + n_panel * 128 + wn + lr;
#pragma unroll
        for (int nf = 0; nf < 4; nf++) Op[nf * 16] = acc[mf][nf][j];
      }
  } else {
#pragma unroll
    for (int mf = 0; mf < 4; mf++)
#pragma unroll
      for (int j = 0; j < 4; j++) {
        const int gi = rbeg + m0 + wm + mf * 16 + rq + j;
        if (gi < rend) {
          const int slot = perm[gi];
          const float g = gates[slot];
          short* Cp = yb + (size_t)slot * D_MODEL + bxn * 128 + wn + lr;
#pragma unroll
          for (int nf = 0; nf < 4; nf++) Cp[nf * 16] = f2b(g * acc[mf][nf][j]);
        }
      }
  }
#undef K2STAGE
#undef LDA2
#undef LDB2
#undef MM2
}

// ---- final combine: out = (out(shared) + y0 + y1) / 3 ----
__global__ __launch_bounds__(256) void combine_kernel(float* __restrict__ out,
                                                      const short* __restrict__ yb) {
  const float inv3 = 1.0f / 3.0f;
#pragma unroll
  for (int rep = 0; rep < 2; rep++) {
    const int i = (rep * 2048 + blockIdx.x) * 256 + threadIdx.x;  // float4 index
    const int base = i * 4;
    const int tok = base >> 10;
    const int col = base & (D_MODEL - 1);
    float4 s = *(float4*)&out[base];
    const short4 y0 = *(const short4*)&yb[(size_t)(tok * 2) * D_MODEL + col];
    const short4 y1 = *(const short4*)&yb[(size_t)(tok * 2 + 1) * D_MODEL + col];
    s.x = (s.x + b2f(y0.x) + b2f(y1.x)) * inv3;
    s.y = (s.y + b2f(y0.y) + b2f(y1.y)) * inv3;
    s.z = (s.z + b2f(y0.z) + b2f(y1.z)) * inv3;
    s.w = (s.w + b2f(y0.w) + b2f(y1.w)) * inv3;
    *(float4*)&out[base] = s;
  }
}

// ---------------- launch ----------------
extern "C" void kernel_launch(void* const* d_in, const int* in_sizes, int n_in,
                              void* d_out, int out_size, void* d_ws, size_t ws_size,
                              hipStream_t stream) {
  const float* x = (const float*)d_in[0];
  const float* temb = (const float*)d_in[1];
  const float* rw = (const float*)d_in[2];
  const float* rbias = (const float*)d_in[3];
  const float* w1 = (const float*)d_in[4];
  const float* w3 = (const float*)d_in[5];
  const float* w2 = (const float*)d_in[6];
  const float* W1e = (const float*)d_in[7];
  const float* W2e = (const float*)d_in[8];
  float* out = (float*)d_out;

  const size_t MB = 1ull << 20;
  char* w = (char*)d_ws;
  short* xb    = (short*)(w + 0 * MB);
  short* w13I  = (short*)(w + 8 * MB);
  short* w2T   = (short*)(w + 16 * MB);
  short* W1eT  = (short*)(w + 20 * MB);
  short* W2eT  = (short*)(w + 36 * MB);
  short* ubuf  = (short*)(w + 52 * MB);
  short* hexpb = (short*)(w + 68 * MB);
  short* yb    = (short*)(w + 84 * MB);
  float* gates = (float*)(w + 100 * MB);
  int* topk    = (int*)(w + 100 * MB + 32 * 1024);
  int* perm    = (int*)(w + 100 * MB + 64 * 1024);
  int* meta    = (int*)(w + 100 * MB + 96 * 1024);
  int* offs    = meta;
  int* te      = meta + 16;
  int* tm      = meta + 128;
  int* ntile   = meta + 256;

  hipFuncSetAttribute((const void*)&moe_k1,
                      hipFuncAttributeMaxDynamicSharedMemorySize, 65536);
  hipFuncSetAttribute((const void*)&moe_k2,
                      hipFuncAttributeMaxDynamicSharedMemorySize, 65536);

  // prep
  tr_all<<<5632, 256, 0, stream>>>(w1, w3, w2, W1e, W2e, w13I, w2T, W1eT, W2eT);
  router_kernel<<<NTOK / 4, 256, 0, stream>>>(x, temb, rw, rbias, xb, topk, gates);
  group_kernel<<<1, 1024, 0, stream>>>(topk, perm, offs, te, tm, ntile);

  // kernel-1: G1 (1024 blocks) || GG1 (576 blocks), proven template, 2 blk/CU
  moe_k1<<<1600, 256, 65536, stream>>>(xb, w13I, W1eT, ubuf, hexpb, perm, offs,
                                       te, tm, ntile);

  // kernel-2: G2 (256, -> out f32) || GG2 (576, -> yb), 2 blk/CU
  moe_k2<<<832, 256, 65536, stream>>>(ubuf, w2T, hexpb, W2eT, out, yb, perm,
                                      offs, gates, te, tm, ntile);

  // combine
  combine_kernel<<<2048, 256, 0, stream>>>(out, yb);
}